// Round 10
// baseline (427.885 us; speedup 1.0000x reference)
//
#include <hip/hip_runtime.h>
#include <math.h>

#define N_NODES 20000
#define E0      320000
#define E_TOT   (E0 + N_NODES)   /* 340000: edges + self-loops */
#define N_GRAPHS 64
#define IN_DIM  39
#define HID     128
#define HEADS   4
#define HHID    (HEADS * HID)    /* 512 */
#define NUM_CONV 3
#define PRED_HID 32
#define NEG_SLOPE 0.2f

__device__ __forceinline__ int esrc(const int* __restrict__ ei, int e) {
    return e < E0 ? ei[e] : (e - E0);
}
__device__ __forceinline__ int edst(const int* __restrict__ ei, int e) {
    return e < E0 ? ei[E0 + e] : (e - E0);
}

// ---------------- CSR build ----------------
__global__ void k_deg(const int* __restrict__ ei, int* __restrict__ deg) {
    int e = blockIdx.x * blockDim.x + threadIdx.x;
    if (e >= E_TOT) return;
    atomicAdd(&deg[edst(ei, e)], 1);
}

__global__ __launch_bounds__(1024) void k_scan(const int* __restrict__ deg,
                                               int* __restrict__ row_ptr,
                                               int* __restrict__ cursor) {
    __shared__ int part[1024];
    const int CHUNK = 20;
    int t = threadIdx.x;
    int base = t * CHUNK;
    int s = 0;
    for (int i = 0; i < CHUNK; i++) {
        int idx = base + i;
        if (idx < N_NODES) s += deg[idx];
    }
    part[t] = s;
    __syncthreads();
    for (int off = 1; off < 1024; off <<= 1) {
        int v = (t >= off) ? part[t - off] : 0;
        __syncthreads();
        part[t] += v;
        __syncthreads();
    }
    int run = part[t] - s;
    for (int i = 0; i < CHUNK; i++) {
        int idx = base + i;
        if (idx < N_NODES) {
            row_ptr[idx] = run;
            cursor[idx]  = run;
            run += deg[idx];
        }
    }
    if (t == 1023) row_ptr[N_NODES] = part[1023];
}

__global__ void k_scatter(const int* __restrict__ ei, int* __restrict__ cursor,
                          int* __restrict__ csr_src, int* __restrict__ csr_dst) {
    int e = blockIdx.x * blockDim.x + threadIdx.x;
    if (e >= E_TOT) return;
    int d = edst(ei, e);
    int pos = atomicAdd(&cursor[d], 1);
    csr_src[pos] = esrc(ei, e);
    csr_dst[pos] = d;
}

// ---------------- embedding ----------------
__global__ __launch_bounds__(128) void k_emb(const float* __restrict__ nf,
                                             const float* __restrict__ W,
                                             const float* __restrict__ b,
                                             float* __restrict__ x) {
    __shared__ float f[IN_DIM];
    int n = blockIdx.x, t = threadIdx.x;
    if (t < IN_DIM) f[t] = nf[(size_t)n * IN_DIM + t];
    __syncthreads();
    float acc = b[t];
#pragma unroll
    for (int k = 0; k < IN_DIM; k++) acc += f[k] * W[k * HID + t];
    x[(size_t)n * HID + t] = acc;
}

// ---------------- Wsd precompute ----------------
__global__ __launch_bounds__(128) void k_wsd(const float* __restrict__ lin_W,
                                             const float* __restrict__ attS,
                                             const float* __restrict__ attD,
                                             float* __restrict__ Wsd) {
    int l = blockIdx.x >> 3, j = blockIdx.x & 7, k = threadIdx.x;
    int h = j & 3;
    const float* Wl = lin_W + (size_t)l * HID * HHID;
    const float* av = ((j < 4) ? attS : attD) + ((size_t)l * HEADS + h) * HID;
    const float* wr = Wl + (size_t)k * HHID + h * HID;
    float dot = 0.f;
#pragma unroll 4
    for (int f = 0; f < HID; f++) dot += wr[f] * av[f];
    Wsd[(size_t)l * 8 * HID + j * HID + k] = dot;
}

// ---------------- attention projection (layer 0 only) ----------------
__global__ __launch_bounds__(256) void k_attproj(const float* __restrict__ x,
                                                 const float* __restrict__ WsdL,
                                                 float* __restrict__ A8) {
    __shared__ float sW[8 * HID];
    for (int i = threadIdx.x; i < 8 * HID; i += 256) sW[i] = WsdL[i];
    __syncthreads();
    int wid = threadIdx.x >> 6, lane = threadIdx.x & 63;
    int n = blockIdx.x * 4 + wid;
    if (n >= N_NODES) return;
    float2 xv = *(const float2*)(x + (size_t)n * HID + lane * 2);
    float p[8];
#pragma unroll
    for (int j = 0; j < 8; j++) {
        float v = xv.x * sW[j * HID + lane * 2] + xv.y * sW[j * HID + lane * 2 + 1];
#pragma unroll
        for (int off = 32; off; off >>= 1) v += __shfl_xor(v, off, 64);
        p[j] = v;
    }
    if (lane == 0) {
        *(float4*)(A8 + (size_t)n * 8)     = make_float4(p[0], p[1], p[2], p[3]);
        *(float4*)(A8 + (size_t)n * 8 + 4) = make_float4(p[4], p[5], p[6], p[7]);
    }
}

// ---------------- per-edge exp in CSR slot order (once per edge) ----------------
__global__ void k_edge(const int* __restrict__ csr_src, const int* __restrict__ csr_dst,
                       const float* __restrict__ A8, float* __restrict__ expE) {
    int j = blockIdx.x * blockDim.x + threadIdx.x;
    if (j >= E_TOT) return;
    int s = csr_src[j], d = csr_dst[j];
    float4 vs = *(const float4*)(A8 + (size_t)s * 8);
    float4 vd = *(const float4*)(A8 + (size_t)d * 8 + 4);
    float4 r;
    float v;
    v = vs.x + vd.x; v = fmaxf(v, NEG_SLOPE * v); r.x = expf(v);
    v = vs.y + vd.y; v = fmaxf(v, NEG_SLOPE * v); r.y = expf(v);
    v = vs.z + vd.z; v = fmaxf(v, NEG_SLOPE * v); r.z = expf(v);
    v = vs.w + vd.w; v = fmaxf(v, NEG_SLOPE * v); r.w = expf(v);
    *(float4*)(expE + (size_t)j * HEADS) = r;
}

// ---------------- aggregation: 8-edge grouped loads for MLP ----------------
__global__ __launch_bounds__(256) void k_aggr(const float* __restrict__ x,
                                              const int* __restrict__ row_ptr,
                                              const int* __restrict__ csr_src,
                                              const float* __restrict__ expE,  // CSR order
                                              float* __restrict__ agg) {
    int wid = threadIdx.x >> 6, lane = threadIdx.x & 63;
    int n = blockIdx.x * 4 + wid;
    if (n >= N_NODES) return;
    int beg = row_ptr[n], end = row_ptr[n + 1];
    float a0x = 0.f, a0y = 0.f, a1x = 0.f, a1y = 0.f;
    float a2x = 0.f, a2y = 0.f, a3x = 0.f, a3y = 0.f;
    float d0 = 0.f, d1 = 0.f, d2 = 0.f, d3 = 0.f;
    size_t lo = (size_t)(lane * 2);
    int i = beg;
    for (; i + 8 <= end; i += 8) {
        int ss[8];
#pragma unroll
        for (int u = 0; u < 8; u++) ss[u] = csr_src[i + u];
        float4 ee[8];
#pragma unroll
        for (int u = 0; u < 8; u++) ee[u] = *(const float4*)(expE + (size_t)(i + u) * HEADS);
        float2 xx[8];
#pragma unroll
        for (int u = 0; u < 8; u++) xx[u] = *(const float2*)(x + (size_t)ss[u] * HID + lo);
#pragma unroll
        for (int u = 0; u < 8; u++) {
            a0x += ee[u].x * xx[u].x; a0y += ee[u].x * xx[u].y;
            a1x += ee[u].y * xx[u].x; a1y += ee[u].y * xx[u].y;
            a2x += ee[u].z * xx[u].x; a2y += ee[u].z * xx[u].y;
            a3x += ee[u].w * xx[u].x; a3y += ee[u].w * xx[u].y;
            d0 += ee[u].x; d1 += ee[u].y; d2 += ee[u].z; d3 += ee[u].w;
        }
    }
    for (; i < end; i++) {
        int s0 = csr_src[i];
        float4 e0 = *(const float4*)(expE + (size_t)i * HEADS);
        float2 xv0 = *(const float2*)(x + (size_t)s0 * HID + lo);
        a0x += e0.x * xv0.x; a0y += e0.x * xv0.y;
        a1x += e0.y * xv0.x; a1y += e0.y * xv0.y;
        a2x += e0.z * xv0.x; a2y += e0.z * xv0.y;
        a3x += e0.w * xv0.x; a3y += e0.w * xv0.y;
        d0 += e0.x; d1 += e0.y; d2 += e0.z; d3 += e0.w;
    }
    float i0 = 1.f / d0, i1 = 1.f / d1, i2 = 1.f / d2, i3 = 1.f / d3;
    float* ag = agg + (size_t)n * HHID;
    *(float2*)(ag + 0 * HID + lo) = make_float2(a0x * i0, a0y * i0);
    *(float2*)(ag + 1 * HID + lo) = make_float2(a1x * i1, a1y * i1);
    *(float2*)(ag + 2 * HID + lo) = make_float2(a2x * i2, a2y * i2);
    *(float2*)(ag + 3 * HID + lo) = make_float2(a3x * i3, a3y * i3);
}

// ---------------- GEMM2 split-K: BM=128, 8x8 micro-tile, BK=32 ----------------
#define G2_BM 128
#define G2_KSPLIT 4
__global__ __launch_bounds__(256) void k_gemm2(const float* __restrict__ agg,
                                               const float* __restrict__ W,   // [128][512]
                                               float* __restrict__ part, int M) {
    __shared__ float At[32][G2_BM];   // transposed + XOR-swizzled, 16 KB
    __shared__ float Bs[32][HID];     // 16 KB
    int tid = threadIdx.x;
    int row0 = blockIdx.x * G2_BM;
    int ks = blockIdx.y;
    int ty = tid >> 4, tx = tid & 15;   // ty 0..15, tx 0..15
    int r0 = ty * 8, c0 = tx * 4;
    float acc[8][8] = {};

#pragma unroll
    for (int kt = 0; kt < 4; kt++) {
        int kbase = ks * 128 + kt * 32;
        __syncthreads();
        // A tile: 128 rows x 32 k -> At[k][sw(r,k)] ; 4 float4 per thread
#pragma unroll
        for (int i = 0; i < 4; i++) {
            int idx = tid + i * 256;
            int r = idx >> 3;        // 0..127
            int c4 = idx & 7;        // k-quad 0..7
            int gr = row0 + r;
            float4 v = make_float4(0.f, 0.f, 0.f, 0.f);
            if (gr < M) v = *(const float4*)(agg + (size_t)gr * HHID + kbase + c4 * 4);
            // physical col of logical row r at k-quad c4
            int sw = (((r >> 2) ^ c4) << 2) + (r & 3);
            At[c4 * 4 + 0][sw] = v.x;
            At[c4 * 4 + 1][sw] = v.y;
            At[c4 * 4 + 2][sw] = v.z;
            At[c4 * 4 + 3][sw] = v.w;
        }
        // B tile: 32 kg x 128 f (permuted lin_W view); 4 float4 per thread
#pragma unroll
        for (int i = 0; i < 4; i++) {
            int idx = tid + i * 256;
            int kr = idx >> 5;       // 0..31
            int c4 = idx & 31;
            int kg = kbase + kr;
            int hd = kg >> 7, kk = kg & 127;
            *(float4*)(&Bs[kr][c4 * 4]) =
                *(const float4*)(W + (size_t)kk * HHID + hd * HID + c4 * 4);
        }
        __syncthreads();
#pragma unroll 2
        for (int k = 0; k < 32; k++) {
            int kq = k >> 2;
            float4 a1 = *(float4*)(&At[k][((((2 * ty)     ^ kq) & 31) << 2)]);
            float4 a2 = *(float4*)(&At[k][((((2 * ty + 1) ^ kq) & 31) << 2)]);
            float4 b1 = *(float4*)(&Bs[k][c0]);
            float4 b2 = *(float4*)(&Bs[k][c0 + 64]);
            float av[8] = {a1.x, a1.y, a1.z, a1.w, a2.x, a2.y, a2.z, a2.w};
            float bv[8] = {b1.x, b1.y, b1.z, b1.w, b2.x, b2.y, b2.z, b2.w};
#pragma unroll
            for (int i = 0; i < 8; i++) {
#pragma unroll
                for (int j = 0; j < 8; j++) acc[i][j] += av[i] * bv[j];
            }
        }
    }
    float* pb = part + (size_t)ks * M * HID;
#pragma unroll
    for (int i = 0; i < 8; i++) {
        int gr = row0 + r0 + i;
        if (gr < M) {
            *(float4*)(pb + (size_t)gr * HID + c0) =
                make_float4(acc[i][0], acc[i][1], acc[i][2], acc[i][3]);
            *(float4*)(pb + (size_t)gr * HID + c0 + 64) =
                make_float4(acc[i][4], acc[i][5], acc[i][6], acc[i][7]);
        }
    }
}

// ---------------- finish: xn = 0.25*sum(part) + bias ; also next-layer A8 ----------------
__global__ __launch_bounds__(256) void k_gfin(const float* __restrict__ part,
                                              const float* __restrict__ bias,
                                              const float* __restrict__ WsdL,
                                              float* __restrict__ xn,
                                              float* __restrict__ A8, int M) {
    __shared__ float sW[8 * HID];
    for (int i = threadIdx.x; i < 8 * HID; i += 256) sW[i] = WsdL[i];
    __syncthreads();
    int wid = threadIdx.x >> 6, lane = threadIdx.x & 63;
    int n = blockIdx.x * 4 + wid;
    if (n >= M) return;
    size_t off = (size_t)n * HID + lane * 2;
    size_t str = (size_t)M * HID;
    float2 p0 = *(const float2*)(part + off);
    float2 p1 = *(const float2*)(part + str + off);
    float2 p2 = *(const float2*)(part + 2 * str + off);
    float2 p3 = *(const float2*)(part + 3 * str + off);
    float2 bb = *(const float2*)(bias + lane * 2);
    float2 xv;
    xv.x = 0.25f * (p0.x + p1.x + p2.x + p3.x) + bb.x;
    xv.y = 0.25f * (p0.y + p1.y + p2.y + p3.y) + bb.y;
    *(float2*)(xn + off) = xv;
    float p[8];
#pragma unroll
    for (int j = 0; j < 8; j++) {
        float v = xv.x * sW[j * HID + lane * 2] + xv.y * sW[j * HID + lane * 2 + 1];
#pragma unroll
        for (int o = 32; o; o >>= 1) v += __shfl_xor(v, o, 64);
        p[j] = v;
    }
    if (lane == 0) {
        *(float4*)(A8 + (size_t)n * 8)     = make_float4(p[0], p[1], p[2], p[3]);
        *(float4*)(A8 + (size_t)n * 8 + 4) = make_float4(p[4], p[5], p[6], p[7]);
    }
}

// ---------------- pooling ----------------
#define POOL_NPB 64
__global__ __launch_bounds__(128) void k_pool(const float* __restrict__ x,
                                              const int* __restrict__ batch,
                                              float* __restrict__ g_sum,
                                              int* __restrict__ g_cnt) {
    int t = threadIdx.x;
    int n0 = blockIdx.x * POOL_NPB;
    int n1 = n0 + POOL_NPB; if (n1 > N_NODES) n1 = N_NODES;
    if (n0 >= n1) return;
    int cur = batch[n0];
    float acc = 0.f;
    int cnt = 0;
    for (int n = n0; n < n1; n++) {
        int b = batch[n];
        if (b != cur) {
            atomicAdd(&g_sum[cur * HID + t], acc);
            if (t == 0) atomicAdd(&g_cnt[cur], cnt);
            acc = 0.f; cnt = 0; cur = b;
        }
        acc += x[(size_t)n * HID + t];
        cnt++;
    }
    atomicAdd(&g_sum[cur * HID + t], acc);
    if (t == 0) atomicAdd(&g_cnt[cur], cnt);
}

// ---------------- head ----------------
__global__ __launch_bounds__(64) void k_head(const float* __restrict__ g_sum,
                                             const int* __restrict__ g_cnt,
                                             const float* __restrict__ fcW,
                                             const float* __restrict__ fcb,
                                             const float* __restrict__ outW,
                                             const float* __restrict__ outb,
                                             float* __restrict__ out) {
    int g = blockIdx.x, t = threadIdx.x;
    float inv = 1.f / fmaxf((float)g_cnt[g], 1.f);
    float val = 0.f;
    if (t < PRED_HID) {
        float dot = fcb[t];
        for (int f = 0; f < HID; f++)
            dot += (g_sum[g * HID + f] * inv) * fcW[f * PRED_HID + t];
        val = dot * outW[t];
    }
#pragma unroll
    for (int off = 32; off; off >>= 1) val += __shfl_xor(val, off, 64);
    if (t == 0) out[g] = val + outb[0];
}

extern "C" void kernel_launch(void* const* d_in, const int* in_sizes, int n_in,
                              void* d_out, int out_size, void* d_ws, size_t ws_size,
                              hipStream_t stream) {
    const float* node_feat = (const float*)d_in[0];
    const int*   edge_index = (const int*)d_in[1];
    const int*   batch     = (const int*)d_in[2];
    const float* emb_W     = (const float*)d_in[3];
    const float* emb_b     = (const float*)d_in[4];
    const float* lin_W     = (const float*)d_in[5];   // [3][128][512]
    const float* att_src   = (const float*)d_in[6];
    const float* att_dst   = (const float*)d_in[7];
    const float* conv_b    = (const float*)d_in[8];
    const float* fc_W      = (const float*)d_in[9];
    const float* fc_b      = (const float*)d_in[10];
    const float* out_W     = (const float*)d_in[11];
    const float* out_b     = (const float*)d_in[12];
    float* out = (float*)d_out;

    char* p = (char*)d_ws;
    auto alloc = [&](size_t bytes) {
        void* r = (void*)p;
        p += (bytes + 255) & ~(size_t)255;
        return r;
    };
    float* x0      = (float*)alloc((size_t)N_NODES * HID * 4);
    float* x1      = (float*)alloc((size_t)N_NODES * HID * 4);
    float* agg     = (float*)alloc((size_t)N_NODES * HHID * 4);
    float* part    = (float*)alloc((size_t)G2_KSPLIT * N_NODES * HID * 4);
    float* A8      = (float*)alloc((size_t)N_NODES * 8 * 4);
    float* Wsd     = (float*)alloc((size_t)NUM_CONV * 8 * HID * 4);
    float* expE    = (float*)alloc((size_t)E_TOT * HEADS * 4);
    int*   deg     = (int*)alloc((size_t)(N_NODES + 1) * 4);
    int*   row_ptr = (int*)alloc((size_t)(N_NODES + 1) * 4);
    int*   cursor  = (int*)alloc((size_t)N_NODES * 4);
    int*   csr_src = (int*)alloc((size_t)E_TOT * 4);
    int*   csr_dst = (int*)alloc((size_t)E_TOT * 4);
    float* g_sum   = (float*)alloc((size_t)N_GRAPHS * HID * 4);
    int*   g_cnt   = (int*)alloc((size_t)N_GRAPHS * 4);

    const int EB = (E_TOT + 255) / 256;
    const int NB4 = (N_NODES + 3) / 4;

    // CSR build (topology shared across layers)
    hipMemsetAsync(deg, 0, (size_t)N_NODES * 4, stream);
    k_deg<<<EB, 256, 0, stream>>>(edge_index, deg);
    k_scan<<<1, 1024, 0, stream>>>(deg, row_ptr, cursor);
    k_scatter<<<EB, 256, 0, stream>>>(edge_index, cursor, csr_src, csr_dst);

    // per-layer attention-vector precompute
    k_wsd<<<NUM_CONV * 8, 128, 0, stream>>>(lin_W, att_src, att_dst, Wsd);

    // embedding + layer-0 attention projection
    k_emb<<<N_NODES, 128, 0, stream>>>(node_feat, emb_W, emb_b, x0);
    k_attproj<<<NB4, 256, 0, stream>>>(x0, Wsd, A8);

    float* xin = x0;
    float* xout = x1;
    for (int l = 0; l < NUM_CONV; l++) {
        const float* Wl = lin_W + (size_t)l * HID * HHID;
        const float* bl = conv_b + (size_t)l * HID;
        int lnext = (l + 1 < NUM_CONV) ? l + 1 : NUM_CONV - 1;

        k_edge<<<EB, 256, 0, stream>>>(csr_src, csr_dst, A8, expE);
        k_aggr<<<NB4, 256, 0, stream>>>(xin, row_ptr, csr_src, expE, agg);
        dim3 gg((N_NODES + G2_BM - 1) / G2_BM, G2_KSPLIT);
        k_gemm2<<<gg, 256, 0, stream>>>(agg, Wl, part, N_NODES);
        k_gfin<<<NB4, 256, 0, stream>>>(part, bl, Wsd + (size_t)lnext * 8 * HID,
                                        xout, A8, N_NODES);
        float* tmp = xin; xin = xout; xout = tmp;
    }

    // pooling + head
    hipMemsetAsync(g_sum, 0, (size_t)N_GRAPHS * HID * 4, stream);
    hipMemsetAsync(g_cnt, 0, (size_t)N_GRAPHS * 4, stream);
    k_pool<<<(N_NODES + POOL_NPB - 1) / POOL_NPB, 128, 0, stream>>>(xin, batch, g_sum, g_cnt);
    k_head<<<N_GRAPHS, 64, 0, stream>>>(g_sum, g_cnt, fc_W, fc_b,
                                        out_W, out_b, out);
}

// Round 11
// 426.824 us; speedup vs baseline: 1.0025x; 1.0025x over previous
//
#include <hip/hip_runtime.h>
#include <math.h>

#define N_NODES 20000
#define E0      320000
#define E_TOT   (E0 + N_NODES)   /* 340000: edges + self-loops */
#define N_GRAPHS 64
#define IN_DIM  39
#define HID     128
#define HEADS   4
#define HHID    (HEADS * HID)    /* 512 */
#define NUM_CONV 3
#define PRED_HID 32
#define NEG_SLOPE 0.2f

__device__ __forceinline__ int esrc(const int* __restrict__ ei, int e) {
    return e < E0 ? ei[e] : (e - E0);
}
__device__ __forceinline__ int edst(const int* __restrict__ ei, int e) {
    return e < E0 ? ei[E0 + e] : (e - E0);
}

// ---------------- CSR build ----------------
__global__ void k_deg(const int* __restrict__ ei, int* __restrict__ deg) {
    int e = blockIdx.x * blockDim.x + threadIdx.x;
    if (e >= E_TOT) return;
    atomicAdd(&deg[edst(ei, e)], 1);
}

__global__ __launch_bounds__(1024) void k_scan(const int* __restrict__ deg,
                                               int* __restrict__ row_ptr,
                                               int* __restrict__ cursor) {
    __shared__ int part[1024];
    const int CHUNK = 20;
    int t = threadIdx.x;
    int base = t * CHUNK;
    int s = 0;
    for (int i = 0; i < CHUNK; i++) {
        int idx = base + i;
        if (idx < N_NODES) s += deg[idx];
    }
    part[t] = s;
    __syncthreads();
    for (int off = 1; off < 1024; off <<= 1) {
        int v = (t >= off) ? part[t - off] : 0;
        __syncthreads();
        part[t] += v;
        __syncthreads();
    }
    int run = part[t] - s;
    for (int i = 0; i < CHUNK; i++) {
        int idx = base + i;
        if (idx < N_NODES) {
            row_ptr[idx] = run;
            cursor[idx]  = run;
            run += deg[idx];
        }
    }
    if (t == 1023) row_ptr[N_NODES] = part[1023];
}

__global__ void k_scatter(const int* __restrict__ ei, int* __restrict__ cursor,
                          int* __restrict__ csr_src, int* __restrict__ csr_dst) {
    int e = blockIdx.x * blockDim.x + threadIdx.x;
    if (e >= E_TOT) return;
    int d = edst(ei, e);
    int pos = atomicAdd(&cursor[d], 1);
    csr_src[pos] = esrc(ei, e);
    csr_dst[pos] = d;
}

// ---------------- embedding ----------------
__global__ __launch_bounds__(128) void k_emb(const float* __restrict__ nf,
                                             const float* __restrict__ W,
                                             const float* __restrict__ b,
                                             float* __restrict__ x) {
    __shared__ float f[IN_DIM];
    int n = blockIdx.x, t = threadIdx.x;
    if (t < IN_DIM) f[t] = nf[(size_t)n * IN_DIM + t];
    __syncthreads();
    float acc = b[t];
#pragma unroll
    for (int k = 0; k < IN_DIM; k++) acc += f[k] * W[k * HID + t];
    x[(size_t)n * HID + t] = acc;
}

// ---------------- Wsd precompute ----------------
__global__ __launch_bounds__(128) void k_wsd(const float* __restrict__ lin_W,
                                             const float* __restrict__ attS,
                                             const float* __restrict__ attD,
                                             float* __restrict__ Wsd) {
    int l = blockIdx.x >> 3, j = blockIdx.x & 7, k = threadIdx.x;
    int h = j & 3;
    const float* Wl = lin_W + (size_t)l * HID * HHID;
    const float* av = ((j < 4) ? attS : attD) + ((size_t)l * HEADS + h) * HID;
    const float* wr = Wl + (size_t)k * HHID + h * HID;
    float dot = 0.f;
#pragma unroll 4
    for (int f = 0; f < HID; f++) dot += wr[f] * av[f];
    Wsd[(size_t)l * 8 * HID + j * HID + k] = dot;
}

// ---------------- attention projection (layer 0 only) ----------------
__global__ __launch_bounds__(256) void k_attproj(const float* __restrict__ x,
                                                 const float* __restrict__ WsdL,
                                                 float* __restrict__ A8) {
    __shared__ float sW[8 * HID];
    for (int i = threadIdx.x; i < 8 * HID; i += 256) sW[i] = WsdL[i];
    __syncthreads();
    int wid = threadIdx.x >> 6, lane = threadIdx.x & 63;
    int n = blockIdx.x * 4 + wid;
    if (n >= N_NODES) return;
    float2 xv = *(const float2*)(x + (size_t)n * HID + lane * 2);
    float p[8];
#pragma unroll
    for (int j = 0; j < 8; j++) {
        float v = xv.x * sW[j * HID + lane * 2] + xv.y * sW[j * HID + lane * 2 + 1];
#pragma unroll
        for (int off = 32; off; off >>= 1) v += __shfl_xor(v, off, 64);
        p[j] = v;
    }
    if (lane == 0) {
        *(float4*)(A8 + (size_t)n * 8)     = make_float4(p[0], p[1], p[2], p[3]);
        *(float4*)(A8 + (size_t)n * 8 + 4) = make_float4(p[4], p[5], p[6], p[7]);
    }
}

// ---------------- per-edge exp in CSR slot order (once per edge) ----------------
__global__ void k_edge(const int* __restrict__ csr_src, const int* __restrict__ csr_dst,
                       const float* __restrict__ A8, float* __restrict__ expE) {
    int j = blockIdx.x * blockDim.x + threadIdx.x;
    if (j >= E_TOT) return;
    int s = csr_src[j], d = csr_dst[j];
    float4 vs = *(const float4*)(A8 + (size_t)s * 8);
    float4 vd = *(const float4*)(A8 + (size_t)d * 8 + 4);
    float4 r;
    float v;
    v = vs.x + vd.x; v = fmaxf(v, NEG_SLOPE * v); r.x = expf(v);
    v = vs.y + vd.y; v = fmaxf(v, NEG_SLOPE * v); r.y = expf(v);
    v = vs.z + vd.z; v = fmaxf(v, NEG_SLOPE * v); r.z = expf(v);
    v = vs.w + vd.w; v = fmaxf(v, NEG_SLOPE * v); r.w = expf(v);
    *(float4*)(expE + (size_t)j * HEADS) = r;
}

// ---------------- aggregation: 8-edge grouped loads, 128-VGPR budget ----------------
__global__ __launch_bounds__(256, 4) void k_aggr(const float* __restrict__ x,
                                                 const int* __restrict__ row_ptr,
                                                 const int* __restrict__ csr_src,
                                                 const float* __restrict__ expE,  // CSR order
                                                 float* __restrict__ agg) {
    int wid = threadIdx.x >> 6, lane = threadIdx.x & 63;
    int n = blockIdx.x * 4 + wid;
    if (n >= N_NODES) return;
    int beg = row_ptr[n], end = row_ptr[n + 1];
    float a0x = 0.f, a0y = 0.f, a1x = 0.f, a1y = 0.f;
    float a2x = 0.f, a2y = 0.f, a3x = 0.f, a3y = 0.f;
    float d0 = 0.f, d1 = 0.f, d2 = 0.f, d3 = 0.f;
    size_t lo = (size_t)(lane * 2);
    int i = beg;
    for (; i + 8 <= end; i += 8) {
        int ss[8];
#pragma unroll
        for (int u = 0; u < 8; u++) ss[u] = csr_src[i + u];
        float4 ee[8];
#pragma unroll
        for (int u = 0; u < 8; u++) ee[u] = *(const float4*)(expE + (size_t)(i + u) * HEADS);
        float2 xx[8];
#pragma unroll
        for (int u = 0; u < 8; u++) xx[u] = *(const float2*)(x + (size_t)ss[u] * HID + lo);
#pragma unroll
        for (int u = 0; u < 8; u++) {
            a0x += ee[u].x * xx[u].x; a0y += ee[u].x * xx[u].y;
            a1x += ee[u].y * xx[u].x; a1y += ee[u].y * xx[u].y;
            a2x += ee[u].z * xx[u].x; a2y += ee[u].z * xx[u].y;
            a3x += ee[u].w * xx[u].x; a3y += ee[u].w * xx[u].y;
            d0 += ee[u].x; d1 += ee[u].y; d2 += ee[u].z; d3 += ee[u].w;
        }
    }
    for (; i < end; i++) {
        int s0 = csr_src[i];
        float4 e0 = *(const float4*)(expE + (size_t)i * HEADS);
        float2 xv0 = *(const float2*)(x + (size_t)s0 * HID + lo);
        a0x += e0.x * xv0.x; a0y += e0.x * xv0.y;
        a1x += e0.y * xv0.x; a1y += e0.y * xv0.y;
        a2x += e0.z * xv0.x; a2y += e0.z * xv0.y;
        a3x += e0.w * xv0.x; a3y += e0.w * xv0.y;
        d0 += e0.x; d1 += e0.y; d2 += e0.z; d3 += e0.w;
    }
    float i0 = 1.f / d0, i1 = 1.f / d1, i2 = 1.f / d2, i3 = 1.f / d3;
    float* ag = agg + (size_t)n * HHID;
    *(float2*)(ag + 0 * HID + lo) = make_float2(a0x * i0, a0y * i0);
    *(float2*)(ag + 1 * HID + lo) = make_float2(a1x * i1, a1y * i1);
    *(float2*)(ag + 2 * HID + lo) = make_float2(a2x * i2, a2y * i2);
    *(float2*)(ag + 3 * HID + lo) = make_float2(a3x * i3, a3y * i3);
}

// ---------------- GEMM2 split-K: BM=128, 8x8 micro-tile, BK=32, 128-VGPR budget ----------------
#define G2_BM 128
#define G2_KSPLIT 4
__global__ __launch_bounds__(256, 4) void k_gemm2(const float* __restrict__ agg,
                                                  const float* __restrict__ W,   // [128][512]
                                                  float* __restrict__ part, int M) {
    __shared__ float At[32][G2_BM];   // transposed + XOR-swizzled, 16 KB
    __shared__ float Bs[32][HID];     // 16 KB
    int tid = threadIdx.x;
    int row0 = blockIdx.x * G2_BM;
    int ks = blockIdx.y;
    int ty = tid >> 4, tx = tid & 15;   // ty 0..15, tx 0..15
    int r0 = ty * 8, c0 = tx * 4;
    float acc[8][8] = {};

#pragma unroll
    for (int kt = 0; kt < 4; kt++) {
        int kbase = ks * 128 + kt * 32;
        __syncthreads();
        // A tile: 128 rows x 32 k -> At[k][sw(r,k)] ; 4 float4 per thread
#pragma unroll
        for (int i = 0; i < 4; i++) {
            int idx = tid + i * 256;
            int r = idx >> 3;        // 0..127
            int c4 = idx & 7;        // k-quad 0..7
            int gr = row0 + r;
            float4 v = make_float4(0.f, 0.f, 0.f, 0.f);
            if (gr < M) v = *(const float4*)(agg + (size_t)gr * HHID + kbase + c4 * 4);
            int sw = (((r >> 2) ^ c4) << 2) + (r & 3);
            At[c4 * 4 + 0][sw] = v.x;
            At[c4 * 4 + 1][sw] = v.y;
            At[c4 * 4 + 2][sw] = v.z;
            At[c4 * 4 + 3][sw] = v.w;
        }
        // B tile: 32 kg x 128 f (permuted lin_W view); 4 float4 per thread
#pragma unroll
        for (int i = 0; i < 4; i++) {
            int idx = tid + i * 256;
            int kr = idx >> 5;       // 0..31
            int c4 = idx & 31;
            int kg = kbase + kr;
            int hd = kg >> 7, kk = kg & 127;
            *(float4*)(&Bs[kr][c4 * 4]) =
                *(const float4*)(W + (size_t)kk * HHID + hd * HID + c4 * 4);
        }
        __syncthreads();
#pragma unroll 2
        for (int k = 0; k < 32; k++) {
            int kq = k >> 2;
            float4 a1 = *(float4*)(&At[k][((((2 * ty)     ^ kq) & 31) << 2)]);
            float4 a2 = *(float4*)(&At[k][((((2 * ty + 1) ^ kq) & 31) << 2)]);
            float4 b1 = *(float4*)(&Bs[k][c0]);
            float4 b2 = *(float4*)(&Bs[k][c0 + 64]);
            acc[0][0] += a1.x * b1.x; acc[0][1] += a1.x * b1.y; acc[0][2] += a1.x * b1.z; acc[0][3] += a1.x * b1.w;
            acc[0][4] += a1.x * b2.x; acc[0][5] += a1.x * b2.y; acc[0][6] += a1.x * b2.z; acc[0][7] += a1.x * b2.w;
            acc[1][0] += a1.y * b1.x; acc[1][1] += a1.y * b1.y; acc[1][2] += a1.y * b1.z; acc[1][3] += a1.y * b1.w;
            acc[1][4] += a1.y * b2.x; acc[1][5] += a1.y * b2.y; acc[1][6] += a1.y * b2.z; acc[1][7] += a1.y * b2.w;
            acc[2][0] += a1.z * b1.x; acc[2][1] += a1.z * b1.y; acc[2][2] += a1.z * b1.z; acc[2][3] += a1.z * b1.w;
            acc[2][4] += a1.z * b2.x; acc[2][5] += a1.z * b2.y; acc[2][6] += a1.z * b2.z; acc[2][7] += a1.z * b2.w;
            acc[3][0] += a1.w * b1.x; acc[3][1] += a1.w * b1.y; acc[3][2] += a1.w * b1.z; acc[3][3] += a1.w * b1.w;
            acc[3][4] += a1.w * b2.x; acc[3][5] += a1.w * b2.y; acc[3][6] += a1.w * b2.z; acc[3][7] += a1.w * b2.w;
            acc[4][0] += a2.x * b1.x; acc[4][1] += a2.x * b1.y; acc[4][2] += a2.x * b1.z; acc[4][3] += a2.x * b1.w;
            acc[4][4] += a2.x * b2.x; acc[4][5] += a2.x * b2.y; acc[4][6] += a2.x * b2.z; acc[4][7] += a2.x * b2.w;
            acc[5][0] += a2.y * b1.x; acc[5][1] += a2.y * b1.y; acc[5][2] += a2.y * b1.z; acc[5][3] += a2.y * b1.w;
            acc[5][4] += a2.y * b2.x; acc[5][5] += a2.y * b2.y; acc[5][6] += a2.y * b2.z; acc[5][7] += a2.y * b2.w;
            acc[6][0] += a2.z * b1.x; acc[6][1] += a2.z * b1.y; acc[6][2] += a2.z * b1.z; acc[6][3] += a2.z * b1.w;
            acc[6][4] += a2.z * b2.x; acc[6][5] += a2.z * b2.y; acc[6][6] += a2.z * b2.z; acc[6][7] += a2.z * b2.w;
            acc[7][0] += a2.w * b1.x; acc[7][1] += a2.w * b1.y; acc[7][2] += a2.w * b1.z; acc[7][3] += a2.w * b1.w;
            acc[7][4] += a2.w * b2.x; acc[7][5] += a2.w * b2.y; acc[7][6] += a2.w * b2.z; acc[7][7] += a2.w * b2.w;
        }
    }
    float* pb = part + (size_t)ks * M * HID;
#pragma unroll
    for (int i = 0; i < 8; i++) {
        int gr = row0 + r0 + i;
        if (gr < M) {
            *(float4*)(pb + (size_t)gr * HID + c0) =
                make_float4(acc[i][0], acc[i][1], acc[i][2], acc[i][3]);
            *(float4*)(pb + (size_t)gr * HID + c0 + 64) =
                make_float4(acc[i][4], acc[i][5], acc[i][6], acc[i][7]);
        }
    }
}

// ---------------- finish: xn = 0.25*sum(part) + bias ; also next-layer A8 ----------------
__global__ __launch_bounds__(256) void k_gfin(const float* __restrict__ part,
                                              const float* __restrict__ bias,
                                              const float* __restrict__ WsdL,
                                              float* __restrict__ xn,
                                              float* __restrict__ A8, int M) {
    __shared__ float sW[8 * HID];
    for (int i = threadIdx.x; i < 8 * HID; i += 256) sW[i] = WsdL[i];
    __syncthreads();
    int wid = threadIdx.x >> 6, lane = threadIdx.x & 63;
    int n = blockIdx.x * 4 + wid;
    if (n >= M) return;
    size_t off = (size_t)n * HID + lane * 2;
    size_t str = (size_t)M * HID;
    float2 p0 = *(const float2*)(part + off);
    float2 p1 = *(const float2*)(part + str + off);
    float2 p2 = *(const float2*)(part + 2 * str + off);
    float2 p3 = *(const float2*)(part + 3 * str + off);
    float2 bb = *(const float2*)(bias + lane * 2);
    float2 xv;
    xv.x = 0.25f * (p0.x + p1.x + p2.x + p3.x) + bb.x;
    xv.y = 0.25f * (p0.y + p1.y + p2.y + p3.y) + bb.y;
    *(float2*)(xn + off) = xv;
    float p[8];
#pragma unroll
    for (int j = 0; j < 8; j++) {
        float v = xv.x * sW[j * HID + lane * 2] + xv.y * sW[j * HID + lane * 2 + 1];
#pragma unroll
        for (int o = 32; o; o >>= 1) v += __shfl_xor(v, o, 64);
        p[j] = v;
    }
    if (lane == 0) {
        *(float4*)(A8 + (size_t)n * 8)     = make_float4(p[0], p[1], p[2], p[3]);
        *(float4*)(A8 + (size_t)n * 8 + 4) = make_float4(p[4], p[5], p[6], p[7]);
    }
}

// ---------------- pooling ----------------
#define POOL_NPB 64
__global__ __launch_bounds__(128) void k_pool(const float* __restrict__ x,
                                              const int* __restrict__ batch,
                                              float* __restrict__ g_sum,
                                              int* __restrict__ g_cnt) {
    int t = threadIdx.x;
    int n0 = blockIdx.x * POOL_NPB;
    int n1 = n0 + POOL_NPB; if (n1 > N_NODES) n1 = N_NODES;
    if (n0 >= n1) return;
    int cur = batch[n0];
    float acc = 0.f;
    int cnt = 0;
    for (int n = n0; n < n1; n++) {
        int b = batch[n];
        if (b != cur) {
            atomicAdd(&g_sum[cur * HID + t], acc);
            if (t == 0) atomicAdd(&g_cnt[cur], cnt);
            acc = 0.f; cnt = 0; cur = b;
        }
        acc += x[(size_t)n * HID + t];
        cnt++;
    }
    atomicAdd(&g_sum[cur * HID + t], acc);
    if (t == 0) atomicAdd(&g_cnt[cur], cnt);
}

// ---------------- head ----------------
__global__ __launch_bounds__(64) void k_head(const float* __restrict__ g_sum,
                                             const int* __restrict__ g_cnt,
                                             const float* __restrict__ fcW,
                                             const float* __restrict__ fcb,
                                             const float* __restrict__ outW,
                                             const float* __restrict__ outb,
                                             float* __restrict__ out) {
    int g = blockIdx.x, t = threadIdx.x;
    float inv = 1.f / fmaxf((float)g_cnt[g], 1.f);
    float val = 0.f;
    if (t < PRED_HID) {
        float dot = fcb[t];
        for (int f = 0; f < HID; f++)
            dot += (g_sum[g * HID + f] * inv) * fcW[f * PRED_HID + t];
        val = dot * outW[t];
    }
#pragma unroll
    for (int off = 32; off; off >>= 1) val += __shfl_xor(val, off, 64);
    if (t == 0) out[g] = val + outb[0];
}

extern "C" void kernel_launch(void* const* d_in, const int* in_sizes, int n_in,
                              void* d_out, int out_size, void* d_ws, size_t ws_size,
                              hipStream_t stream) {
    const float* node_feat = (const float*)d_in[0];
    const int*   edge_index = (const int*)d_in[1];
    const int*   batch     = (const int*)d_in[2];
    const float* emb_W     = (const float*)d_in[3];
    const float* emb_b     = (const float*)d_in[4];
    const float* lin_W     = (const float*)d_in[5];   // [3][128][512]
    const float* att_src   = (const float*)d_in[6];
    const float* att_dst   = (const float*)d_in[7];
    const float* conv_b    = (const float*)d_in[8];
    const float* fc_W      = (const float*)d_in[9];
    const float* fc_b      = (const float*)d_in[10];
    const float* out_W     = (const float*)d_in[11];
    const float* out_b     = (const float*)d_in[12];
    float* out = (float*)d_out;

    char* p = (char*)d_ws;
    auto alloc = [&](size_t bytes) {
        void* r = (void*)p;
        p += (bytes + 255) & ~(size_t)255;
        return r;
    };
    float* x0      = (float*)alloc((size_t)N_NODES * HID * 4);
    float* x1      = (float*)alloc((size_t)N_NODES * HID * 4);
    float* agg     = (float*)alloc((size_t)N_NODES * HHID * 4);
    float* part    = (float*)alloc((size_t)G2_KSPLIT * N_NODES * HID * 4);
    float* A8      = (float*)alloc((size_t)N_NODES * 8 * 4);
    float* Wsd     = (float*)alloc((size_t)NUM_CONV * 8 * HID * 4);
    float* expE    = (float*)alloc((size_t)E_TOT * HEADS * 4);
    int*   deg     = (int*)alloc((size_t)(N_NODES + 1) * 4);
    int*   row_ptr = (int*)alloc((size_t)(N_NODES + 1) * 4);
    int*   cursor  = (int*)alloc((size_t)N_NODES * 4);
    int*   csr_src = (int*)alloc((size_t)E_TOT * 4);
    int*   csr_dst = (int*)alloc((size_t)E_TOT * 4);
    float* g_sum   = (float*)alloc((size_t)N_GRAPHS * HID * 4);
    int*   g_cnt   = (int*)alloc((size_t)N_GRAPHS * 4);

    const int EB = (E_TOT + 255) / 256;
    const int NB4 = (N_NODES + 3) / 4;

    // CSR build (topology shared across layers)
    hipMemsetAsync(deg, 0, (size_t)N_NODES * 4, stream);
    k_deg<<<EB, 256, 0, stream>>>(edge_index, deg);
    k_scan<<<1, 1024, 0, stream>>>(deg, row_ptr, cursor);
    k_scatter<<<EB, 256, 0, stream>>>(edge_index, cursor, csr_src, csr_dst);

    // per-layer attention-vector precompute
    k_wsd<<<NUM_CONV * 8, 128, 0, stream>>>(lin_W, att_src, att_dst, Wsd);

    // embedding + layer-0 attention projection
    k_emb<<<N_NODES, 128, 0, stream>>>(node_feat, emb_W, emb_b, x0);
    k_attproj<<<NB4, 256, 0, stream>>>(x0, Wsd, A8);

    float* xin = x0;
    float* xout = x1;
    for (int l = 0; l < NUM_CONV; l++) {
        const float* Wl = lin_W + (size_t)l * HID * HHID;
        const float* bl = conv_b + (size_t)l * HID;
        int lnext = (l + 1 < NUM_CONV) ? l + 1 : NUM_CONV - 1;

        k_edge<<<EB, 256, 0, stream>>>(csr_src, csr_dst, A8, expE);
        k_aggr<<<NB4, 256, 0, stream>>>(xin, row_ptr, csr_src, expE, agg);
        dim3 gg((N_NODES + G2_BM - 1) / G2_BM, G2_KSPLIT);
        k_gemm2<<<gg, 256, 0, stream>>>(agg, Wl, part, N_NODES);
        k_gfin<<<NB4, 256, 0, stream>>>(part, bl, Wsd + (size_t)lnext * 8 * HID,
                                        xout, A8, N_NODES);
        float* tmp = xin; xin = xout; xout = tmp;
    }

    // pooling + head
    hipMemsetAsync(g_sum, 0, (size_t)N_GRAPHS * HID * 4, stream);
    hipMemsetAsync(g_cnt, 0, (size_t)N_GRAPHS * 4, stream);
    k_pool<<<(N_NODES + POOL_NPB - 1) / POOL_NPB, 128, 0, stream>>>(xin, batch, g_sum, g_cnt);
    k_head<<<N_GRAPHS, 64, 0, stream>>>(g_sum, g_cnt, fc_W, fc_b,
                                        out_W, out_b, out);
}

// Round 12
// 410.852 us; speedup vs baseline: 1.0415x; 1.0389x over previous
//
#include <hip/hip_runtime.h>
#include <math.h>

#define N_NODES 20000
#define E0      320000
#define E_TOT   (E0 + N_NODES)   /* 340000: edges + self-loops */
#define N_GRAPHS 64
#define IN_DIM  39
#define HID     128
#define HEADS   4
#define HHID    (HEADS * HID)    /* 512 */
#define NUM_CONV 3
#define PRED_HID 32
#define NEG_SLOPE 0.2f

__device__ __forceinline__ int esrc(const int* __restrict__ ei, int e) {
    return e < E0 ? ei[e] : (e - E0);
}
__device__ __forceinline__ int edst(const int* __restrict__ ei, int e) {
    return e < E0 ? ei[E0 + e] : (e - E0);
}

// ---------------- CSR build ----------------
__global__ void k_deg(const int* __restrict__ ei, int* __restrict__ deg) {
    int e = blockIdx.x * blockDim.x + threadIdx.x;
    if (e >= E_TOT) return;
    atomicAdd(&deg[edst(ei, e)], 1);
}

__global__ __launch_bounds__(1024) void k_scan(const int* __restrict__ deg,
                                               int* __restrict__ row_ptr,
                                               int* __restrict__ cursor) {
    __shared__ int part[1024];
    const int CHUNK = 20;
    int t = threadIdx.x;
    int base = t * CHUNK;
    int s = 0;
    for (int i = 0; i < CHUNK; i++) {
        int idx = base + i;
        if (idx < N_NODES) s += deg[idx];
    }
    part[t] = s;
    __syncthreads();
    for (int off = 1; off < 1024; off <<= 1) {
        int v = (t >= off) ? part[t - off] : 0;
        __syncthreads();
        part[t] += v;
        __syncthreads();
    }
    int run = part[t] - s;
    for (int i = 0; i < CHUNK; i++) {
        int idx = base + i;
        if (idx < N_NODES) {
            row_ptr[idx] = run;
            cursor[idx]  = run;
            run += deg[idx];
        }
    }
    if (t == 1023) row_ptr[N_NODES] = part[1023];
}

__global__ void k_scatter(const int* __restrict__ ei, int* __restrict__ cursor,
                          int* __restrict__ csr_src) {
    int e = blockIdx.x * blockDim.x + threadIdx.x;
    if (e >= E_TOT) return;
    int d = edst(ei, e);
    int pos = atomicAdd(&cursor[d], 1);
    csr_src[pos] = esrc(ei, e);
}

// ---------------- embedding ----------------
__global__ __launch_bounds__(128) void k_emb(const float* __restrict__ nf,
                                             const float* __restrict__ W,
                                             const float* __restrict__ b,
                                             float* __restrict__ x) {
    __shared__ float f[IN_DIM];
    int n = blockIdx.x, t = threadIdx.x;
    if (t < IN_DIM) f[t] = nf[(size_t)n * IN_DIM + t];
    __syncthreads();
    float acc = b[t];
#pragma unroll
    for (int k = 0; k < IN_DIM; k++) acc += f[k] * W[k * HID + t];
    x[(size_t)n * HID + t] = acc;
}

// ---------------- Wsd precompute ----------------
__global__ __launch_bounds__(128) void k_wsd(const float* __restrict__ lin_W,
                                             const float* __restrict__ attS,
                                             const float* __restrict__ attD,
                                             float* __restrict__ Wsd) {
    int l = blockIdx.x >> 3, j = blockIdx.x & 7, k = threadIdx.x;
    int h = j & 3;
    const float* Wl = lin_W + (size_t)l * HID * HHID;
    const float* av = ((j < 4) ? attS : attD) + ((size_t)l * HEADS + h) * HID;
    const float* wr = Wl + (size_t)k * HHID + h * HID;
    float dot = 0.f;
#pragma unroll 4
    for (int f = 0; f < HID; f++) dot += wr[f] * av[f];
    Wsd[(size_t)l * 8 * HID + j * HID + k] = dot;
}

// ---------------- attention projection (layer 0 only) ----------------
__global__ __launch_bounds__(256) void k_attproj(const float* __restrict__ x,
                                                 const float* __restrict__ WsdL,
                                                 float* __restrict__ A8) {
    __shared__ float sW[8 * HID];
    for (int i = threadIdx.x; i < 8 * HID; i += 256) sW[i] = WsdL[i];
    __syncthreads();
    int wid = threadIdx.x >> 6, lane = threadIdx.x & 63;
    int n = blockIdx.x * 4 + wid;
    if (n >= N_NODES) return;
    float2 xv = *(const float2*)(x + (size_t)n * HID + lane * 2);
    float p[8];
#pragma unroll
    for (int j = 0; j < 8; j++) {
        float v = xv.x * sW[j * HID + lane * 2] + xv.y * sW[j * HID + lane * 2 + 1];
#pragma unroll
        for (int off = 32; off; off >>= 1) v += __shfl_xor(v, off, 64);
        p[j] = v;
    }
    if (lane == 0) {
        *(float4*)(A8 + (size_t)n * 8)     = make_float4(p[0], p[1], p[2], p[3]);
        *(float4*)(A8 + (size_t)n * 8 + 4) = make_float4(p[4], p[5], p[6], p[7]);
    }
}

// ---------------- aggregation with fused lane-parallel edge softmax ----------------
// 4-edge groups; lanes 0-15 compute one (edge,head) exp each, shfl-broadcast to all.
__global__ __launch_bounds__(256) void k_aggr(const float* __restrict__ x,
                                              const int* __restrict__ row_ptr,
                                              const int* __restrict__ csr_src,
                                              const float* __restrict__ A8,
                                              float* __restrict__ agg) {
    int wid = threadIdx.x >> 6, lane = threadIdx.x & 63;
    int n = blockIdx.x * 4 + wid;
    if (n >= N_NODES) return;
    float4 vd = *(const float4*)(A8 + (size_t)n * 8 + 4);
    int beg = row_ptr[n], end = row_ptr[n + 1];
    float a0x = 0.f, a0y = 0.f, a1x = 0.f, a1y = 0.f;
    float a2x = 0.f, a2y = 0.f, a3x = 0.f, a3y = 0.f;
    float d0 = 0.f, d1 = 0.f, d2 = 0.f, d3 = 0.f;
    size_t lo = (size_t)(lane * 2);
    // per-lane (edge,head) assignment for the exp stage
    int eu = lane >> 2, eh = lane & 3;   // lanes 0..15 active
    float vdh = (eh == 0) ? vd.x : (eh == 1) ? vd.y : (eh == 2) ? vd.z : vd.w;
    int i = beg;
    for (; i + 4 <= end; i += 4) {
        int s0 = csr_src[i];
        int s1 = csr_src[i + 1];
        int s2 = csr_src[i + 2];
        int s3 = csr_src[i + 3];
        // lanes 0-15: compute exp(leaky(a_s[ss[eu]][eh] + a_d[n][eh]))
        float e = 0.f;
        if (lane < 16) {
            int su = (eu == 0) ? s0 : (eu == 1) ? s1 : (eu == 2) ? s2 : s3;
            float v = A8[(size_t)su * 8 + eh] + vdh;
            v = fmaxf(v, NEG_SLOPE * v);
            e = __expf(v);
        }
        float2 xv0 = *(const float2*)(x + (size_t)s0 * HID + lo);
        float2 xv1 = *(const float2*)(x + (size_t)s1 * HID + lo);
        float2 xv2 = *(const float2*)(x + (size_t)s2 * HID + lo);
        float2 xv3 = *(const float2*)(x + (size_t)s3 * HID + lo);
        float e00 = __shfl(e, 0, 64),  e01 = __shfl(e, 1, 64),  e02 = __shfl(e, 2, 64),  e03 = __shfl(e, 3, 64);
        float e10 = __shfl(e, 4, 64),  e11 = __shfl(e, 5, 64),  e12 = __shfl(e, 6, 64),  e13 = __shfl(e, 7, 64);
        float e20 = __shfl(e, 8, 64),  e21 = __shfl(e, 9, 64),  e22 = __shfl(e, 10, 64), e23 = __shfl(e, 11, 64);
        float e30 = __shfl(e, 12, 64), e31 = __shfl(e, 13, 64), e32 = __shfl(e, 14, 64), e33 = __shfl(e, 15, 64);
        a0x += e00 * xv0.x; a0y += e00 * xv0.y;
        a1x += e01 * xv0.x; a1y += e01 * xv0.y;
        a2x += e02 * xv0.x; a2y += e02 * xv0.y;
        a3x += e03 * xv0.x; a3y += e03 * xv0.y;
        d0 += e00; d1 += e01; d2 += e02; d3 += e03;
        a0x += e10 * xv1.x; a0y += e10 * xv1.y;
        a1x += e11 * xv1.x; a1y += e11 * xv1.y;
        a2x += e12 * xv1.x; a2y += e12 * xv1.y;
        a3x += e13 * xv1.x; a3y += e13 * xv1.y;
        d0 += e10; d1 += e11; d2 += e12; d3 += e13;
        a0x += e20 * xv2.x; a0y += e20 * xv2.y;
        a1x += e21 * xv2.x; a1y += e21 * xv2.y;
        a2x += e22 * xv2.x; a2y += e22 * xv2.y;
        a3x += e23 * xv2.x; a3y += e23 * xv2.y;
        d0 += e20; d1 += e21; d2 += e22; d3 += e23;
        a0x += e30 * xv3.x; a0y += e30 * xv3.y;
        a1x += e31 * xv3.x; a1y += e31 * xv3.y;
        a2x += e32 * xv3.x; a2y += e32 * xv3.y;
        a3x += e33 * xv3.x; a3y += e33 * xv3.y;
        d0 += e30; d1 += e31; d2 += e32; d3 += e33;
    }
    for (; i < end; i++) {
        int s0 = csr_src[i];
        float4 vs = *(const float4*)(A8 + (size_t)s0 * 8);
        float2 xv0 = *(const float2*)(x + (size_t)s0 * HID + lo);
        float v0 = vs.x + vd.x; v0 = fmaxf(v0, NEG_SLOPE * v0); float e0 = __expf(v0);
        float v1 = vs.y + vd.y; v1 = fmaxf(v1, NEG_SLOPE * v1); float e1 = __expf(v1);
        float v2 = vs.z + vd.z; v2 = fmaxf(v2, NEG_SLOPE * v2); float e2 = __expf(v2);
        float v3 = vs.w + vd.w; v3 = fmaxf(v3, NEG_SLOPE * v3); float e3 = __expf(v3);
        a0x += e0 * xv0.x; a0y += e0 * xv0.y;
        a1x += e1 * xv0.x; a1y += e1 * xv0.y;
        a2x += e2 * xv0.x; a2y += e2 * xv0.y;
        a3x += e3 * xv0.x; a3y += e3 * xv0.y;
        d0 += e0; d1 += e1; d2 += e2; d3 += e3;
    }
    float i0 = 1.f / d0, i1 = 1.f / d1, i2 = 1.f / d2, i3 = 1.f / d3;
    float* ag = agg + (size_t)n * HHID;
    *(float2*)(ag + 0 * HID + lo) = make_float2(a0x * i0, a0y * i0);
    *(float2*)(ag + 1 * HID + lo) = make_float2(a1x * i1, a1y * i1);
    *(float2*)(ag + 2 * HID + lo) = make_float2(a2x * i2, a2y * i2);
    *(float2*)(ag + 3 * HID + lo) = make_float2(a3x * i3, a3y * i3);
}

// ---------------- GEMM2 split-K (R7/R9-proven config) ----------------
#define G2_BM 64
#define G2_KSPLIT 4
__global__ __launch_bounds__(256) void k_gemm2(const float* __restrict__ agg,
                                               const float* __restrict__ W,   // [128][512]
                                               float* __restrict__ part, int M) {
    __shared__ float At[64][G2_BM];   // transposed + XOR-swizzled
    __shared__ float Bs[64][HID];
    int tid = threadIdx.x;
    int row0 = blockIdx.x * G2_BM;
    int ks = blockIdx.y;
    int ty = tid >> 4, tx = tid & 15;
    int r0 = ty * 4, c0 = tx * 4;
    float acc[4][8] = {};

#pragma unroll
    for (int kt = 0; kt < 2; kt++) {
        int kbase = ks * 128 + kt * 64;
        __syncthreads();
#pragma unroll
        for (int i = 0; i < 4; i++) {
            int idx = tid + i * 256;
            int r = idx >> 4;
            int c4 = idx & 15;
            int gr = row0 + r;
            float4 v = make_float4(0.f, 0.f, 0.f, 0.f);
            if (gr < M) v = *(const float4*)(agg + (size_t)gr * HHID + kbase + c4 * 4);
            int sw = (((r >> 2) ^ c4) << 2) + (r & 3);
            At[c4 * 4 + 0][sw] = v.x;
            At[c4 * 4 + 1][sw] = v.y;
            At[c4 * 4 + 2][sw] = v.z;
            At[c4 * 4 + 3][sw] = v.w;
        }
#pragma unroll
        for (int i = 0; i < 8; i++) {
            int idx = tid + i * 256;
            int kr = idx >> 5;
            int c4 = idx & 31;
            int kg = kbase + kr;
            int hd = kg >> 7, kk = kg & 127;
            *(float4*)(&Bs[kr][c4 * 4]) =
                *(const float4*)(W + (size_t)kk * HHID + hd * HID + c4 * 4);
        }
        __syncthreads();
#pragma unroll 4
        for (int k = 0; k < 64; k++) {
            float4 av = *(float4*)(&At[k][((ty ^ (k >> 2)) << 2)]);
            float4 b1 = *(float4*)(&Bs[k][c0]);
            float4 b2 = *(float4*)(&Bs[k][c0 + 64]);
            acc[0][0] += av.x * b1.x; acc[0][1] += av.x * b1.y; acc[0][2] += av.x * b1.z; acc[0][3] += av.x * b1.w;
            acc[0][4] += av.x * b2.x; acc[0][5] += av.x * b2.y; acc[0][6] += av.x * b2.z; acc[0][7] += av.x * b2.w;
            acc[1][0] += av.y * b1.x; acc[1][1] += av.y * b1.y; acc[1][2] += av.y * b1.z; acc[1][3] += av.y * b1.w;
            acc[1][4] += av.y * b2.x; acc[1][5] += av.y * b2.y; acc[1][6] += av.y * b2.z; acc[1][7] += av.y * b2.w;
            acc[2][0] += av.z * b1.x; acc[2][1] += av.z * b1.y; acc[2][2] += av.z * b1.z; acc[2][3] += av.z * b1.w;
            acc[2][4] += av.z * b2.x; acc[2][5] += av.z * b2.y; acc[2][6] += av.z * b2.z; acc[2][7] += av.z * b2.w;
            acc[3][0] += av.w * b1.x; acc[3][1] += av.w * b1.y; acc[3][2] += av.w * b1.z; acc[3][3] += av.w * b1.w;
            acc[3][4] += av.w * b2.x; acc[3][5] += av.w * b2.y; acc[3][6] += av.w * b2.z; acc[3][7] += av.w * b2.w;
        }
    }
    float* pb = part + (size_t)ks * M * HID;
#pragma unroll
    for (int i = 0; i < 4; i++) {
        int gr = row0 + r0 + i;
        if (gr < M) {
            *(float4*)(pb + (size_t)gr * HID + c0) =
                make_float4(acc[i][0], acc[i][1], acc[i][2], acc[i][3]);
            *(float4*)(pb + (size_t)gr * HID + c0 + 64) =
                make_float4(acc[i][4], acc[i][5], acc[i][6], acc[i][7]);
        }
    }
}

// ---------------- finish: xn = 0.25*sum(part) + bias ; also next-layer A8 ----------------
__global__ __launch_bounds__(256) void k_gfin(const float* __restrict__ part,
                                              const float* __restrict__ bias,
                                              const float* __restrict__ WsdL,
                                              float* __restrict__ xn,
                                              float* __restrict__ A8, int M) {
    __shared__ float sW[8 * HID];
    for (int i = threadIdx.x; i < 8 * HID; i += 256) sW[i] = WsdL[i];
    __syncthreads();
    int wid = threadIdx.x >> 6, lane = threadIdx.x & 63;
    int n = blockIdx.x * 4 + wid;
    if (n >= M) return;
    size_t off = (size_t)n * HID + lane * 2;
    size_t str = (size_t)M * HID;
    float2 p0 = *(const float2*)(part + off);
    float2 p1 = *(const float2*)(part + str + off);
    float2 p2 = *(const float2*)(part + 2 * str + off);
    float2 p3 = *(const float2*)(part + 3 * str + off);
    float2 bb = *(const float2*)(bias + lane * 2);
    float2 xv;
    xv.x = 0.25f * (p0.x + p1.x + p2.x + p3.x) + bb.x;
    xv.y = 0.25f * (p0.y + p1.y + p2.y + p3.y) + bb.y;
    *(float2*)(xn + off) = xv;
    float p[8];
#pragma unroll
    for (int j = 0; j < 8; j++) {
        float v = xv.x * sW[j * HID + lane * 2] + xv.y * sW[j * HID + lane * 2 + 1];
#pragma unroll
        for (int o = 32; o; o >>= 1) v += __shfl_xor(v, o, 64);
        p[j] = v;
    }
    if (lane == 0) {
        *(float4*)(A8 + (size_t)n * 8)     = make_float4(p[0], p[1], p[2], p[3]);
        *(float4*)(A8 + (size_t)n * 8 + 4) = make_float4(p[4], p[5], p[6], p[7]);
    }
}

// ---------------- pooling ----------------
#define POOL_NPB 64
__global__ __launch_bounds__(128) void k_pool(const float* __restrict__ x,
                                              const int* __restrict__ batch,
                                              float* __restrict__ g_sum,
                                              int* __restrict__ g_cnt) {
    int t = threadIdx.x;
    int n0 = blockIdx.x * POOL_NPB;
    int n1 = n0 + POOL_NPB; if (n1 > N_NODES) n1 = N_NODES;
    if (n0 >= n1) return;
    int cur = batch[n0];
    float acc = 0.f;
    int cnt = 0;
    for (int n = n0; n < n1; n++) {
        int b = batch[n];
        if (b != cur) {
            atomicAdd(&g_sum[cur * HID + t], acc);
            if (t == 0) atomicAdd(&g_cnt[cur], cnt);
            acc = 0.f; cnt = 0; cur = b;
        }
        acc += x[(size_t)n * HID + t];
        cnt++;
    }
    atomicAdd(&g_sum[cur * HID + t], acc);
    if (t == 0) atomicAdd(&g_cnt[cur], cnt);
}

// ---------------- head ----------------
__global__ __launch_bounds__(64) void k_head(const float* __restrict__ g_sum,
                                             const int* __restrict__ g_cnt,
                                             const float* __restrict__ fcW,
                                             const float* __restrict__ fcb,
                                             const float* __restrict__ outW,
                                             const float* __restrict__ outb,
                                             float* __restrict__ out) {
    int g = blockIdx.x, t = threadIdx.x;
    float inv = 1.f / fmaxf((float)g_cnt[g], 1.f);
    float val = 0.f;
    if (t < PRED_HID) {
        float dot = fcb[t];
        for (int f = 0; f < HID; f++)
            dot += (g_sum[g * HID + f] * inv) * fcW[f * PRED_HID + t];
        val = dot * outW[t];
    }
#pragma unroll
    for (int off = 32; off; off >>= 1) val += __shfl_xor(val, off, 64);
    if (t == 0) out[g] = val + outb[0];
}

extern "C" void kernel_launch(void* const* d_in, const int* in_sizes, int n_in,
                              void* d_out, int out_size, void* d_ws, size_t ws_size,
                              hipStream_t stream) {
    const float* node_feat = (const float*)d_in[0];
    const int*   edge_index = (const int*)d_in[1];
    const int*   batch     = (const int*)d_in[2];
    const float* emb_W     = (const float*)d_in[3];
    const float* emb_b     = (const float*)d_in[4];
    const float* lin_W     = (const float*)d_in[5];   // [3][128][512]
    const float* att_src   = (const float*)d_in[6];
    const float* att_dst   = (const float*)d_in[7];
    const float* conv_b    = (const float*)d_in[8];
    const float* fc_W      = (const float*)d_in[9];
    const float* fc_b      = (const float*)d_in[10];
    const float* out_W     = (const float*)d_in[11];
    const float* out_b     = (const float*)d_in[12];
    float* out = (float*)d_out;

    char* p = (char*)d_ws;
    auto alloc = [&](size_t bytes) {
        void* r = (void*)p;
        p += (bytes + 255) & ~(size_t)255;
        return r;
    };
    float* x0      = (float*)alloc((size_t)N_NODES * HID * 4);
    float* x1      = (float*)alloc((size_t)N_NODES * HID * 4);
    float* agg     = (float*)alloc((size_t)N_NODES * HHID * 4);
    float* part    = (float*)alloc((size_t)G2_KSPLIT * N_NODES * HID * 4);
    float* A8      = (float*)alloc((size_t)N_NODES * 8 * 4);
    float* Wsd     = (float*)alloc((size_t)NUM_CONV * 8 * HID * 4);
    int*   deg     = (int*)alloc((size_t)(N_NODES + 1) * 4);
    int*   row_ptr = (int*)alloc((size_t)(N_NODES + 1) * 4);
    int*   cursor  = (int*)alloc((size_t)N_NODES * 4);
    int*   csr_src = (int*)alloc((size_t)E_TOT * 4);
    float* g_sum   = (float*)alloc((size_t)N_GRAPHS * HID * 4);
    int*   g_cnt   = (int*)alloc((size_t)N_GRAPHS * 4);

    const int EB = (E_TOT + 255) / 256;
    const int NB4 = (N_NODES + 3) / 4;

    // CSR build (topology shared across layers)
    hipMemsetAsync(deg, 0, (size_t)N_NODES * 4, stream);
    k_deg<<<EB, 256, 0, stream>>>(edge_index, deg);
    k_scan<<<1, 1024, 0, stream>>>(deg, row_ptr, cursor);
    k_scatter<<<EB, 256, 0, stream>>>(edge_index, cursor, csr_src);

    // per-layer attention-vector precompute
    k_wsd<<<NUM_CONV * 8, 128, 0, stream>>>(lin_W, att_src, att_dst, Wsd);

    // embedding + layer-0 attention projection
    k_emb<<<N_NODES, 128, 0, stream>>>(node_feat, emb_W, emb_b, x0);
    k_attproj<<<NB4, 256, 0, stream>>>(x0, Wsd, A8);

    float* xin = x0;
    float* xout = x1;
    for (int l = 0; l < NUM_CONV; l++) {
        const float* Wl = lin_W + (size_t)l * HID * HHID;
        const float* bl = conv_b + (size_t)l * HID;
        int lnext = (l + 1 < NUM_CONV) ? l + 1 : NUM_CONV - 1;

        k_aggr<<<NB4, 256, 0, stream>>>(xin, row_ptr, csr_src, A8, agg);
        dim3 gg((N_NODES + G2_BM - 1) / G2_BM, G2_KSPLIT);
        k_gemm2<<<gg, 256, 0, stream>>>(agg, Wl, part, N_NODES);
        k_gfin<<<NB4, 256, 0, stream>>>(part, bl, Wsd + (size_t)lnext * 8 * HID,
                                        xout, A8, N_NODES);
        float* tmp = xin; xin = xout; xout = tmp;
    }

    // pooling + head
    hipMemsetAsync(g_sum, 0, (size_t)N_GRAPHS * HID * 4, stream);
    hipMemsetAsync(g_cnt, 0, (size_t)N_GRAPHS * 4, stream);
    k_pool<<<(N_NODES + POOL_NPB - 1) / POOL_NPB, 128, 0, stream>>>(xin, batch, g_sum, g_cnt);
    k_head<<<N_GRAPHS, 64, 0, stream>>>(g_sum, g_cnt, fc_W, fc_b,
                                        out_W, out_b, out);
}